// Round 13
// baseline (1185.307 us; speedup 1.0000x reference)
//
#include <hip/hip_runtime.h>

typedef unsigned long long u64;
typedef unsigned int u32;
typedef float v2f __attribute__((ext_vector_type(2)));

// Problem constants (from reference setup_inputs / NUM_GROUP / GROUP_SIZE)
#define BATCH 32
#define NPTS  8192
#define NGRP  512
#define KNN_K 32

#define FPS_T 512                  // fps block size (8 waves, 2/SIMD)
#define FPS_W (FPS_T / 64)         // 8 waves
#define PPAIR (NPTS / FPS_T / 2)   // 8 point-pairs per thread PER BATCH
#define KNN_WPB 4                  // knn waves per block
#define QCAP 128                   // per-wave LDS candidate buffer depth

// Exact IEEE (no FMA contraction) squared distance: ((dx*dx + dy*dy) + dz*dz)
__device__ __forceinline__ float sq3(float dx, float dy, float dz) {
    return __fadd_rn(__fadd_rn(__fmul_rn(dx, dx), __fmul_rn(dy, dy)), __fmul_rn(dz, dz));
}

// d >= 0 always -> IEEE bits order-monotonic; u64 ascending == (d, idx) lex.
__device__ __forceinline__ u64 packdi(float d, int n) {
    return ((u64)__float_as_uint(d) << 32) | (u32)n;
}

__device__ __forceinline__ u64 umin64(u64 a, u64 b) { return a < b ? a : b; }
__device__ __forceinline__ u64 umax64(u64 a, u64 b) { return a > b ? a : b; }

__device__ __forceinline__ u64 shfl_xor_u64(u64 v, int m) {
    int lo = __shfl_xor((int)(u32)v, m, 64);
    int hi = __shfl_xor((int)(u32)(v >> 32), m, 64);
    return ((u64)(u32)hi << 32) | (u32)lo;
}

__device__ __forceinline__ u64 shfl_u64(u64 v, int src) {
    int lo = __shfl((int)(u32)v, src, 64);
    int hi = __shfl((int)(u32)(v >> 32), src, 64);
    return ((u64)(u32)hi << 32) | (u32)lo;
}

// ---- DPP wave-64 u64-max reduction (result valid in lane 63) --------------
// update_dpp(old=0, bound_ctrl=1): invalid-source lanes read 0; 0 is a safe
// identity (real keys have low32 = ~n >= 0xFFFFE000 > 0).
template <int CTRL>
__device__ __forceinline__ u64 dpp_max_step(u64 k) {
    u32 plo = (u32)__builtin_amdgcn_update_dpp(0, (int)(u32)k, CTRL, 0xF, 0xF, true);
    u32 phi = (u32)__builtin_amdgcn_update_dpp(0, (int)(u32)(k >> 32), CTRL, 0xF, 0xF, true);
    u64 p = ((u64)phi << 32) | plo;
    return k > p ? k : p;
}
__device__ __forceinline__ u64 dpp_wave_max(u64 k) {
    k = dpp_max_step<0x111>(k);  // row_shr:1
    k = dpp_max_step<0x112>(k);  // row_shr:2
    k = dpp_max_step<0x114>(k);  // row_shr:4
    k = dpp_max_step<0x118>(k);  // row_shr:8
    k = dpp_max_step<0x142>(k);  // row_bcast15
    k = dpp_max_step<0x143>(k);  // row_bcast31 -> lane63 = full wave
    return k;
}

// Cross-lane bitonic sort: one u64 per lane -> ascending by lane index.
__device__ __forceinline__ u64 lane_sort64(u64 v, int lane) {
#pragma unroll
    for (int k = 2; k <= 64; k <<= 1) {
#pragma unroll
        for (int j = k >> 1; j > 0; j >>= 1) {
            u64 p = shfl_xor_u64(v, j);
            bool keepmin = (((lane & k) == 0) == ((lane & j) == 0));
            u64 mn = umin64(v, p), mx = umax64(v, p);
            v = keepmin ? mn : mx;
        }
    }
    return v;
}

// m, c ascending-sorted across lanes -> lowest 64 of the 128, sorted.
__device__ __forceinline__ u64 lane_merge64(u64 m, u64 c, int lane) {
    u64 cr = shfl_xor_u64(c, 63);
    u64 z = umin64(m, cr);
#pragma unroll
    for (int dd = 32; dd > 0; dd >>= 1) {
        u64 p = shfl_xor_u64(z, dd);
        u64 mn = umin64(z, p), mx = umax64(z, p);
        z = (lane & dd) ? mx : mn;
    }
    return z;
}

// ---------------------------------------------------------------------------
// Dual-batch interleaved FPS: 16 blocks x 512 threads; block k owns batches
// 2k, 2k+1 (16 pts/thread/batch as 8 v2f pairs; ~160 VGPRs -> 2 waves/SIMD).
// Rationale (R12 post-mortem): single-batch round = ~1330 cyc issue + ~630
// cyc dependent-latency tail that nothing can hide. Interleaving a second
// independent batch fills the tail with real issue work, and both batches
// share one barrier pair per round. No LDS point mirror (won't fit twice):
// winner coords via OWNER-PUBLISH -- after the partial reduce, the owning
// thread writes the 3 coords to s_c (2nd barrier covers it; that's the
// latency the dual-batch ILP hides). Champion in-loop (bd,bi) tracking,
// u64 (d,~n) DPP argmax, double-buffered 8-partial exchange, LDS-buffered
// center output -- all carried from R11.
// ---------------------------------------------------------------------------
__global__ __launch_bounds__(FPS_T) void fps_kernel(const float* __restrict__ in,
                                                    float* __restrict__ centers) {
#pragma clang fp contract(off)
    __shared__ float s_cA[3], s_cB[3];       // current centroid coords
    __shared__ u64 s_keyA[2][FPS_W];         // double-buffered wave partials
    __shared__ u64 s_keyB[2][FPS_W];
    __shared__ float s_outA[NGRP * 3];       // 6 KB center buffer (batch A)
    __shared__ float s_outB[NGRP * 3];       // 6 KB center buffer (batch B)

    const int bA = 2 * blockIdx.x;
    const int bB = bA + 1;
    const int t = threadIdx.x;
    const int w = t >> 6;
    const float* xpA = in + (size_t)bA * 3 * NPTS;
    const float* ypA = xpA + NPTS;
    const float* zpA = xpA + 2 * NPTS;
    const float* xpB = in + (size_t)bB * 3 * NPTS;
    const float* ypB = xpB + NPTS;
    const float* zpB = xpB + 2 * NPTS;

    v2f xrA[PPAIR], yrA[PPAIR], zrA[PPAIR], mdA[PPAIR];
    v2f xrB[PPAIR], yrB[PPAIR], zrB[PPAIR], mdB[PPAIR];
#pragma unroll
    for (int i = 0; i < PPAIR; ++i) {
        int n = i * (2 * FPS_T) + 2 * t;     // pair covers points n, n+1
        xrA[i] = *(const v2f*)(xpA + n);
        yrA[i] = *(const v2f*)(ypA + n);
        zrA[i] = *(const v2f*)(zpA + n);
        xrB[i] = *(const v2f*)(xpB + n);
        yrB[i] = *(const v2f*)(ypB + n);
        zrB[i] = *(const v2f*)(zpB + n);
        mdA[i] = (v2f){1e10f, 1e10f};
        mdB[i] = (v2f){1e10f, 1e10f};
    }
    if (t == 0) {  // farthest starts at index 0 (owned by t0, pair 0, half 0)
        s_cA[0] = xrA[0].x; s_cA[1] = yrA[0].x; s_cA[2] = zrA[0].x;
        s_cB[0] = xrB[0].x; s_cB[1] = yrB[0].x; s_cB[2] = zrB[0].x;
    }
    __syncthreads();

    for (int r = 0; r < NGRP; ++r) {
        const float cAx = s_cA[0], cAy = s_cA[1], cAz = s_cA[2];  // b32 bcast
        const float cBx = s_cB[0], cBy = s_cB[1], cBz = s_cB[2];
        if (t == 0) {  // idxs[r] = PRE-update farthest -> buffer coords
            s_outA[r * 3 + 0] = cAx; s_outA[r * 3 + 1] = cAy; s_outA[r * 3 + 2] = cAz;
            s_outB[r * 3 + 0] = cBx; s_outB[r * 3 + 1] = cBy; s_outB[r * 3 + 2] = cBz;
        }

        // ---- batch A compute (issue) ----
        float bd0 = -1.0f, bd1 = -1.0f;
        int   bi0 = 0,     bi1 = 0;
#pragma unroll
        for (int i = 0; i < PPAIR; ++i) {
            v2f dx = xrA[i] - cAx;
            v2f dy = yrA[i] - cAy;
            v2f dz = zrA[i] - cAz;
            v2f dd = dx * dx + dy * dy + dz * dz;  // 3 mul + 2 add, per-op IEEE
            mdA[i] = __builtin_elementwise_min(mdA[i], dd);
            int n = i * (2 * FPS_T) + 2 * t;
            if (mdA[i].x > bd0) { bd0 = mdA[i].x; bi0 = n; }   // strict >: first max
            if (mdA[i].y > bd1) { bd1 = mdA[i].y; bi1 = n + 1; }
        }
        u64 kA = dpp_wave_max(umax64(
            ((u64)__float_as_uint(bd0) << 32) | (u32)(~(u32)bi0),
            ((u64)__float_as_uint(bd1) << 32) | (u32)(~(u32)bi1)));
        if ((t & 63) == 63) s_keyA[r & 1][w] = kA;

        // ---- batch B compute (issues while A's DPP/LDS latency drains) ----
        bd0 = -1.0f; bd1 = -1.0f; bi0 = 0; bi1 = 0;
#pragma unroll
        for (int i = 0; i < PPAIR; ++i) {
            v2f dx = xrB[i] - cBx;
            v2f dy = yrB[i] - cBy;
            v2f dz = zrB[i] - cBz;
            v2f dd = dx * dx + dy * dy + dz * dz;
            mdB[i] = __builtin_elementwise_min(mdB[i], dd);
            int n = i * (2 * FPS_T) + 2 * t;
            if (mdB[i].x > bd0) { bd0 = mdB[i].x; bi0 = n; }
            if (mdB[i].y > bd1) { bd1 = mdB[i].y; bi1 = n + 1; }
        }
        u64 kB = dpp_wave_max(umax64(
            ((u64)__float_as_uint(bd0) << 32) | (u32)(~(u32)bi0),
            ((u64)__float_as_uint(bd1) << 32) | (u32)(~(u32)bi1)));
        if ((t & 63) == 63) s_keyB[r & 1][w] = kB;

        __syncthreads();

        // ---- reduce partials (A and B overlap via ILP) ----
        u64 mA = s_keyA[r & 1][0];
        u64 mB = s_keyB[r & 1][0];
#pragma unroll
        for (int i = 1; i < FPS_W; ++i) {
            mA = umax64(mA, s_keyA[r & 1][i]);
            mB = umax64(mB, s_keyB[r & 1][i]);
        }
        const int curA = (int)(~(u32)mA);
        const int curB = (int)(~(u32)mB);

        // ---- owner-publish next centroid coords ----
        // n = i*1024 + 2t + h  ->  owner t = (n>>1) & 511, slot = n>>10, h = n&1
        if (t == ((curA >> 1) & (FPS_T - 1))) {
            const int sl = curA >> 10, h = curA & 1;
#pragma unroll
            for (int i = 0; i < PPAIR; ++i) {
                if (i == sl) {
                    s_cA[0] = h ? xrA[i].y : xrA[i].x;
                    s_cA[1] = h ? yrA[i].y : yrA[i].x;
                    s_cA[2] = h ? zrA[i].y : zrA[i].x;
                }
            }
        }
        if (t == ((curB >> 1) & (FPS_T - 1))) {
            const int sl = curB >> 10, h = curB & 1;
#pragma unroll
            for (int i = 0; i < PPAIR; ++i) {
                if (i == sl) {
                    s_cB[0] = h ? xrB[i].y : xrB[i].x;
                    s_cB[1] = h ? yrB[i].y : yrB[i].x;
                    s_cB[2] = h ? zrB[i].y : zrB[i].x;
                }
            }
        }
        __syncthreads();
    }

    // coalesced final write of both batches' centers
    float* cdstA = centers + (size_t)bA * NGRP * 3;
    float* cdstB = centers + (size_t)bB * NGRP * 3;
    for (int i = t; i < NGRP * 3; i += FPS_T) {
        cdstA[i] = s_outA[i];
        cdstB[i] = s_outB[i];
    }
}

// ---------------------------------------------------------------------------
// kNN + gather (R8/R11 proven, ~165 us): one wave per center, wave-
// cooperative exact top-32 with deferred LDS candidate buffer; sort64+merge
// only when >=64 candidates accumulated. Strict < tau filter + unique keys
// => exact; output ascending (d, idx) == stable lax.top_k order.
// ---------------------------------------------------------------------------
__global__ __launch_bounds__(KNN_WPB * 64) void knn_kernel(const float* __restrict__ in,
                                                           const float* __restrict__ centers,
                                                           float* __restrict__ out) {
    __shared__ u64 sbuf[KNN_WPB][QCAP];  // 4 KB candidate buffers

    const int wave = threadIdx.x >> 6;
    const int lane = threadIdx.x & 63;
    const int cid  = blockIdx.x * KNN_WPB + wave;   // [0, B*G)
    const int b    = cid >> 9;                      // /NGRP

    const float* xp = in + (size_t)b * 3 * NPTS;
    const float* yp = xp + NPTS;
    const float* zp = xp + 2 * NPTS;

    const float cx = centers[cid * 3 + 0];
    const float cy = centers[cid * 3 + 1];
    const float cz = centers[cid * 3 + 2];

    // seed: column 0 (points 0..63), exact sorted top-64
    float x = xp[lane], y = yp[lane], z = zp[lane];
    u64 m = packdi(sq3(__fsub_rn(x, cx), __fsub_rn(y, cy), __fsub_rn(z, cz)), lane);
    m = lane_sort64(m, lane);
    u64 tau = shfl_u64(m, 31);
    int cnt = 0;  // wave-uniform buffered-candidate count

    float nx = xp[64 + lane], ny = yp[64 + lane], nz = zp[64 + lane];
#pragma unroll 1
    for (int j = 1; j < NPTS / 64; ++j) {
        x = nx; y = ny; z = nz;
        if (j + 1 < NPTS / 64) {  // 1-deep prefetch
            int n2 = (j + 1) * 64 + lane;
            nx = xp[n2]; ny = yp[n2]; nz = zp[n2];
        }
        float d = sq3(__fsub_rn(x, cx), __fsub_rn(y, cy), __fsub_rn(z, cz));
        u64 kk = packdi(d, j * 64 + lane);
        bool cand = kk < tau;  // strict: excluded keys provably > global 32nd
        u64 mask = __ballot(cand);
        if (mask) {
            u32 below = __builtin_amdgcn_mbcnt_hi(
                (u32)(mask >> 32), __builtin_amdgcn_mbcnt_lo((u32)mask, 0));
            if (cand) sbuf[wave][cnt + below] = kk;
            cnt += (int)__popcll(mask);
            if (cnt >= 64) {  // flush a full batch of 64
                u64 c = sbuf[wave][lane];
                c = lane_sort64(c, lane);
                m = lane_merge64(m, c, lane);
                tau = shfl_u64(m, 31);
                int rem = cnt - 64;
                if (lane < rem) sbuf[wave][lane] = sbuf[wave][64 + lane];
                cnt = rem;
            }
        }
    }
    // drain leftovers (<= 127 keys -> at most 2 batches)
    while (cnt > 0) {
        int take = cnt < 64 ? cnt : 64;
        u64 v = sbuf[wave][lane];
        u64 c = (lane < take) ? v : ~0ull;
        c = lane_sort64(c, lane);
        m = lane_merge64(m, c, lane);
        int rem = cnt - take;
        if (lane < rem) sbuf[wave][lane] = sbuf[wave][64 + lane];
        cnt = rem;
    }

    // lanes 0..31 hold the exact global top-32, ascending (== stable top_k)
    if (lane < KNN_K) {
        int n = (int)(u32)m;
        size_t o = (size_t)cid * (KNN_K * 3) + (size_t)lane * 3;
        out[o + 0] = __fsub_rn(xp[n], cx);
        out[o + 1] = __fsub_rn(yp[n], cy);
        out[o + 2] = __fsub_rn(zp[n], cz);
    }
}

extern "C" void kernel_launch(void* const* d_in, const int* in_sizes, int n_in,
                              void* d_out, int out_size, void* d_ws, size_t ws_size,
                              hipStream_t stream) {
    const float* in  = (const float*)d_in[0];
    float* out       = (float*)d_out;
    float* centers   = out + (size_t)BATCH * NGRP * KNN_K * 3;  // second output section

    fps_kernel<<<BATCH / 2, FPS_T, 0, stream>>>(in, centers);
    knn_kernel<<<(BATCH * NGRP) / KNN_WPB, KNN_WPB * 64, 0, stream>>>(in, centers, out);
}

// Round 14
// 1029.838 us; speedup vs baseline: 1.1510x; 1.1510x over previous
//
#include <hip/hip_runtime.h>

typedef unsigned long long u64;
typedef unsigned int u32;
typedef float v2f __attribute__((ext_vector_type(2)));
typedef float v4f __attribute__((ext_vector_type(4)));

// Problem constants (from reference setup_inputs / NUM_GROUP / GROUP_SIZE)
#define BATCH 32
#define NPTS  8192
#define NGRP  512
#define KNN_K 32

#define FPS_T 512                  // fps block: 8 waves = 2 sub-groups of 4
#define SUB_T 256                  // threads per sub-group (one batch)
#define SUB_W 4                    // waves per sub-group
#define PPAIR (NPTS / SUB_T / 2)   // 16 point-pairs per thread
#define KNN_WPB 4                  // knn waves per block
#define QCAP 128                   // per-wave LDS candidate buffer depth

// Exact IEEE (no FMA contraction) squared distance: ((dx*dx + dy*dy) + dz*dz)
__device__ __forceinline__ float sq3(float dx, float dy, float dz) {
    return __fadd_rn(__fadd_rn(__fmul_rn(dx, dx), __fmul_rn(dy, dy)), __fmul_rn(dz, dz));
}

// d >= 0 always -> IEEE bits order-monotonic; u64 ascending == (d, idx) lex.
__device__ __forceinline__ u64 packdi(float d, int n) {
    return ((u64)__float_as_uint(d) << 32) | (u32)n;
}

__device__ __forceinline__ u64 umin64(u64 a, u64 b) { return a < b ? a : b; }
__device__ __forceinline__ u64 umax64(u64 a, u64 b) { return a > b ? a : b; }

__device__ __forceinline__ u64 shfl_xor_u64(u64 v, int m) {
    int lo = __shfl_xor((int)(u32)v, m, 64);
    int hi = __shfl_xor((int)(u32)(v >> 32), m, 64);
    return ((u64)(u32)hi << 32) | (u32)lo;
}

__device__ __forceinline__ u64 shfl_u64(u64 v, int src) {
    int lo = __shfl((int)(u32)v, src, 64);
    int hi = __shfl((int)(u32)(v >> 32), src, 64);
    return ((u64)(u32)hi << 32) | (u32)lo;
}

// ---- DPP wave-64 u64-max reduction (result valid in lane 63) --------------
// update_dpp(old=0, bound_ctrl=1): invalid-source lanes read 0; 0 is a safe
// identity (real keys have low32 = ~n >= 0xFFFFE000 > 0).
template <int CTRL>
__device__ __forceinline__ u64 dpp_max_step(u64 k) {
    u32 plo = (u32)__builtin_amdgcn_update_dpp(0, (int)(u32)k, CTRL, 0xF, 0xF, true);
    u32 phi = (u32)__builtin_amdgcn_update_dpp(0, (int)(u32)(k >> 32), CTRL, 0xF, 0xF, true);
    u64 p = ((u64)phi << 32) | plo;
    return k > p ? k : p;
}
__device__ __forceinline__ u64 dpp_wave_max(u64 k) {
    k = dpp_max_step<0x111>(k);  // row_shr:1
    k = dpp_max_step<0x112>(k);  // row_shr:2
    k = dpp_max_step<0x114>(k);  // row_shr:4
    k = dpp_max_step<0x118>(k);  // row_shr:8
    k = dpp_max_step<0x142>(k);  // row_bcast15
    k = dpp_max_step<0x143>(k);  // row_bcast31 -> lane63 = full wave
    return k;
}

// Cross-lane bitonic sort: one u64 per lane -> ascending by lane index.
__device__ __forceinline__ u64 lane_sort64(u64 v, int lane) {
#pragma unroll
    for (int k = 2; k <= 64; k <<= 1) {
#pragma unroll
        for (int j = k >> 1; j > 0; j >>= 1) {
            u64 p = shfl_xor_u64(v, j);
            bool keepmin = (((lane & k) == 0) == ((lane & j) == 0));
            u64 mn = umin64(v, p), mx = umax64(v, p);
            v = keepmin ? mn : mx;
        }
    }
    return v;
}

// m, c ascending-sorted across lanes -> lowest 64 of the 128, sorted.
__device__ __forceinline__ u64 lane_merge64(u64 m, u64 c, int lane) {
    u64 cr = shfl_xor_u64(c, 63);
    u64 z = umin64(m, cr);
#pragma unroll
    for (int dd = 32; dd > 0; dd >>= 1) {
        u64 p = shfl_xor_u64(z, dd);
        u64 mn = umin64(z, p), mx = umax64(z, p);
        z = (lane & dd) ? mx : mn;
    }
    return z;
}

// ---------------------------------------------------------------------------
// Sub-group dual-batch FPS: 16 blocks x 512 threads. Waves 0-3 = batch A,
// waves 4-7 = batch B (wave->SIMD round-robin puts one A-wave + one B-wave
// on each SIMD). Per-thread register shape IDENTICAL to the R11 champion
// (16 v2f pairs, one batch) -- R13's spill came from doubling per-thread
// arrays, not from the overlap idea. No barrier in the round loop: each
// sub-group self-syncs via single-write LDS tables (R5 mechanics):
//   s_key[g][r][wg]  -- argmax partials, 0-sentinel (real keys >= 2^32)
//   s_c4[g][r]       -- winner coords as float4, .w = 1.0 marker (single
//                       b128 store; readers poll .w b32, read xyz b32)
// Owner-publish replaces the 96 KB LDS mirror. Sub-groups drift freely;
// each one's ~620 cyc reduce/publish tail is hidden under the sibling's
// distance-loop issue on the shared SIMDs.
// ---------------------------------------------------------------------------
__global__ __launch_bounds__(FPS_T) void fps_kernel(const float* __restrict__ in,
                                                    float* __restrict__ centers) {
#pragma clang fp contract(off)
    __shared__ u64 s_key[2][NGRP][SUB_W];    // 32 KB, write-once per slot
    __shared__ v4f s_c4[2][NGRP + 1];        // 16 KB, write-once per slot

    const int t = threadIdx.x;
    const int w = t >> 6;
    const int g = w >> 2;                    // sub-group 0/1
    const int wg = w & 3;                    // wave within sub-group
    const int tt = t & (SUB_T - 1);          // thread within sub-group
    const int lane = t & 63;
    const int b = 2 * blockIdx.x + g;

    const float* xp = in + (size_t)b * 3 * NPTS;
    const float* yp = xp + NPTS;
    const float* zp = xp + 2 * NPTS;

    // zero the sync tables
    for (int i = t; i < 2 * NGRP * SUB_W; i += FPS_T) ((u64*)s_key)[i] = 0;
    for (int i = t; i < 2 * (NGRP + 1) * 4; i += FPS_T) ((float*)s_c4)[i] = 0.0f;

    v2f xr[PPAIR], yr[PPAIR], zr[PPAIR], md[PPAIR];
#pragma unroll
    for (int i = 0; i < PPAIR; ++i) {
        int n = i * (2 * SUB_T) + 2 * tt;    // pair covers points n, n+1
        xr[i] = *(const v2f*)(xp + n);
        yr[i] = *(const v2f*)(yp + n);
        zr[i] = *(const v2f*)(zp + n);
        md[i] = (v2f){1e10f, 1e10f};
    }
    __syncthreads();  // zeroing complete (only barrier in the kernel)

    if (tt == 0)  // seed round 0: farthest = orig idx 0 (pair 0, half .x)
        s_c4[g][0] = (v4f){xr[0].x, yr[0].x, zr[0].x, 1.0f};

    for (int r = 0; r < NGRP; ++r) {
        // wait for this round's centroid coords (b32 poll on marker)
        volatile float* cw = (volatile float*)&s_c4[g][r];
        while (cw[3] == 0.0f) { }
        const float cx = cw[0], cy = cw[1], cz = cw[2];  // b32 broadcasts

        float bd0 = -1.0f, bd1 = -1.0f;
        int   bi0 = 0,     bi1 = 0;
#pragma unroll
        for (int i = 0; i < PPAIR; ++i) {
            v2f dx = xr[i] - cx;
            v2f dy = yr[i] - cy;
            v2f dz = zr[i] - cz;
            v2f dd = dx * dx + dy * dy + dz * dz;  // 3 mul + 2 add, per-op IEEE
            md[i] = __builtin_elementwise_min(md[i], dd);
            int n = i * (2 * SUB_T) + 2 * tt;
            if (md[i].x > bd0) { bd0 = md[i].x; bi0 = n; }   // strict >: first max
            if (md[i].y > bd1) { bd1 = md[i].y; bi1 = n + 1; }
        }
        u64 k = dpp_wave_max(umax64(
            ((u64)__float_as_uint(bd0) << 32) | (u32)(~(u32)bi0),
            ((u64)__float_as_uint(bd1) << 32) | (u32)(~(u32)bi1)));
        if (lane == 63) s_key[g][r][wg] = k;  // publish wave partial

        // spin until all 4 sub-group partials for round r exist (never 0)
        volatile u64* P = (volatile u64*)&s_key[g][r][0];
        u64 p0, p1, p2, p3;
        do {
            p0 = P[0]; p1 = P[1]; p2 = P[2]; p3 = P[3];
        } while ((p0 == 0) | (p1 == 0) | (p2 == 0) | (p3 == 0));
        u64 m = umax64(umax64(p0, p1), umax64(p2, p3));
        const int cur = (int)(~(u32)m);

        // owner publishes next round's centroid coords (single b128 store)
        // n = i*512 + 2*tt + h  ->  owner tt = (n>>1) & 255, i = n>>9, h = n&1
        if (tt == ((cur >> 1) & (SUB_T - 1))) {
            const int sl = cur >> 9, h = cur & 1;
#pragma unroll
            for (int i = 0; i < PPAIR; ++i) {
                if (i == sl) {
                    s_c4[g][r + 1] = (v4f){h ? xr[i].y : xr[i].x,
                                           h ? yr[i].y : yr[i].x,
                                           h ? zr[i].y : zr[i].x, 1.0f};
                }
            }
        }
    }

    // coalesced final write: s_c4[g][r] holds center r of batch b
    float* cdst = centers + (size_t)b * NGRP * 3;
    for (int i = tt; i < NGRP; i += SUB_T) {
        v4f c = s_c4[g][i];
        cdst[i * 3 + 0] = c.x;
        cdst[i * 3 + 1] = c.y;
        cdst[i * 3 + 2] = c.z;
    }
}

// ---------------------------------------------------------------------------
// kNN + gather (R8/R11 proven, ~165 us): one wave per center, wave-
// cooperative exact top-32 with deferred LDS candidate buffer; sort64+merge
// only when >=64 candidates accumulated. Strict < tau filter + unique keys
// => exact; output ascending (d, idx) == stable lax.top_k order.
// ---------------------------------------------------------------------------
__global__ __launch_bounds__(KNN_WPB * 64) void knn_kernel(const float* __restrict__ in,
                                                           const float* __restrict__ centers,
                                                           float* __restrict__ out) {
    __shared__ u64 sbuf[KNN_WPB][QCAP];  // 4 KB candidate buffers

    const int wave = threadIdx.x >> 6;
    const int lane = threadIdx.x & 63;
    const int cid  = blockIdx.x * KNN_WPB + wave;   // [0, B*G)
    const int b    = cid >> 9;                      // /NGRP

    const float* xp = in + (size_t)b * 3 * NPTS;
    const float* yp = xp + NPTS;
    const float* zp = xp + 2 * NPTS;

    const float cx = centers[cid * 3 + 0];
    const float cy = centers[cid * 3 + 1];
    const float cz = centers[cid * 3 + 2];

    // seed: column 0 (points 0..63), exact sorted top-64
    float x = xp[lane], y = yp[lane], z = zp[lane];
    u64 m = packdi(sq3(__fsub_rn(x, cx), __fsub_rn(y, cy), __fsub_rn(z, cz)), lane);
    m = lane_sort64(m, lane);
    u64 tau = shfl_u64(m, 31);
    int cnt = 0;  // wave-uniform buffered-candidate count

    float nx = xp[64 + lane], ny = yp[64 + lane], nz = zp[64 + lane];
#pragma unroll 1
    for (int j = 1; j < NPTS / 64; ++j) {
        x = nx; y = ny; z = nz;
        if (j + 1 < NPTS / 64) {  // 1-deep prefetch
            int n2 = (j + 1) * 64 + lane;
            nx = xp[n2]; ny = yp[n2]; nz = zp[n2];
        }
        float d = sq3(__fsub_rn(x, cx), __fsub_rn(y, cy), __fsub_rn(z, cz));
        u64 kk = packdi(d, j * 64 + lane);
        bool cand = kk < tau;  // strict: excluded keys provably > global 32nd
        u64 mask = __ballot(cand);
        if (mask) {
            u32 below = __builtin_amdgcn_mbcnt_hi(
                (u32)(mask >> 32), __builtin_amdgcn_mbcnt_lo((u32)mask, 0));
            if (cand) sbuf[wave][cnt + below] = kk;
            cnt += (int)__popcll(mask);
            if (cnt >= 64) {  // flush a full batch of 64
                u64 c = sbuf[wave][lane];
                c = lane_sort64(c, lane);
                m = lane_merge64(m, c, lane);
                tau = shfl_u64(m, 31);
                int rem = cnt - 64;
                if (lane < rem) sbuf[wave][lane] = sbuf[wave][64 + lane];
                cnt = rem;
            }
        }
    }
    // drain leftovers (<= 127 keys -> at most 2 batches)
    while (cnt > 0) {
        int take = cnt < 64 ? cnt : 64;
        u64 v = sbuf[wave][lane];
        u64 c = (lane < take) ? v : ~0ull;
        c = lane_sort64(c, lane);
        m = lane_merge64(m, c, lane);
        int rem = cnt - take;
        if (lane < rem) sbuf[wave][lane] = sbuf[wave][64 + lane];
        cnt = rem;
    }

    // lanes 0..31 hold the exact global top-32, ascending (== stable top_k)
    if (lane < KNN_K) {
        int n = (int)(u32)m;
        size_t o = (size_t)cid * (KNN_K * 3) + (size_t)lane * 3;
        out[o + 0] = __fsub_rn(xp[n], cx);
        out[o + 1] = __fsub_rn(yp[n], cy);
        out[o + 2] = __fsub_rn(zp[n], cz);
    }
}

extern "C" void kernel_launch(void* const* d_in, const int* in_sizes, int n_in,
                              void* d_out, int out_size, void* d_ws, size_t ws_size,
                              hipStream_t stream) {
    const float* in  = (const float*)d_in[0];
    float* out       = (float*)d_out;
    float* centers   = out + (size_t)BATCH * NGRP * KNN_K * 3;  // second output section

    fps_kernel<<<BATCH / 2, FPS_T, 0, stream>>>(in, centers);
    knn_kernel<<<(BATCH * NGRP) / KNN_WPB, KNN_WPB * 64, 0, stream>>>(in, centers, out);
}

// Round 15
// 566.557 us; speedup vs baseline: 2.0921x; 1.8177x over previous
//
#include <hip/hip_runtime.h>

typedef unsigned long long u64;
typedef unsigned int u32;
typedef float v2f __attribute__((ext_vector_type(2)));

// Problem constants (from reference setup_inputs / NUM_GROUP / GROUP_SIZE)
#define BATCH 32
#define NPTS  8192
#define NGRP  512
#define KNN_K 32

#define FPS_T 256                  // fps block (4 waves) -- R4/R11 champion config
#define FPS_W (FPS_T / 64)         // 4 waves
#define PPAIR (NPTS / FPS_T / 2)   // 16 point-PAIRS per thread
#define KNN_WPB 4                  // knn waves per block
#define QCAP 128                   // per-wave LDS candidate buffer depth

// Exact IEEE (no FMA contraction) squared distance: ((dx*dx + dy*dy) + dz*dz)
__device__ __forceinline__ float sq3(float dx, float dy, float dz) {
    return __fadd_rn(__fadd_rn(__fmul_rn(dx, dx), __fmul_rn(dy, dy)), __fmul_rn(dz, dz));
}

// d >= 0 always -> IEEE bits order-monotonic; u64 ascending == (d, idx) lex.
__device__ __forceinline__ u64 packdi(float d, int n) {
    return ((u64)__float_as_uint(d) << 32) | (u32)n;
}

__device__ __forceinline__ u64 umin64(u64 a, u64 b) { return a < b ? a : b; }
__device__ __forceinline__ u64 umax64(u64 a, u64 b) { return a > b ? a : b; }

__device__ __forceinline__ u64 shfl_xor_u64(u64 v, int m) {
    int lo = __shfl_xor((int)(u32)v, m, 64);
    int hi = __shfl_xor((int)(u32)(v >> 32), m, 64);
    return ((u64)(u32)hi << 32) | (u32)lo;
}

__device__ __forceinline__ u64 shfl_u64(u64 v, int src) {
    int lo = __shfl((int)(u32)v, src, 64);
    int hi = __shfl((int)(u32)(v >> 32), src, 64);
    return ((u64)(u32)hi << 32) | (u32)lo;
}

// ---- DPP wave-64 u64-max reduction (result valid in lane 63) --------------
// update_dpp(old=0, bound_ctrl=1): invalid-source lanes read 0; 0 is a safe
// identity (real keys have low32 = ~n >= 0xFFFFE000 > 0).
template <int CTRL>
__device__ __forceinline__ u64 dpp_max_step(u64 k) {
    u32 plo = (u32)__builtin_amdgcn_update_dpp(0, (int)(u32)k, CTRL, 0xF, 0xF, true);
    u32 phi = (u32)__builtin_amdgcn_update_dpp(0, (int)(u32)(k >> 32), CTRL, 0xF, 0xF, true);
    u64 p = ((u64)phi << 32) | plo;
    return k > p ? k : p;
}
__device__ __forceinline__ u64 dpp_wave_max(u64 k) {
    k = dpp_max_step<0x111>(k);  // row_shr:1
    k = dpp_max_step<0x112>(k);  // row_shr:2
    k = dpp_max_step<0x114>(k);  // row_shr:4
    k = dpp_max_step<0x118>(k);  // row_shr:8
    k = dpp_max_step<0x142>(k);  // row_bcast15
    k = dpp_max_step<0x143>(k);  // row_bcast31 -> lane63 = full wave
    return k;
}

// Cross-lane bitonic sort: one u64 per lane -> ascending by lane index.
__device__ __forceinline__ u64 lane_sort64(u64 v, int lane) {
#pragma unroll
    for (int k = 2; k <= 64; k <<= 1) {
#pragma unroll
        for (int j = k >> 1; j > 0; j >>= 1) {
            u64 p = shfl_xor_u64(v, j);
            bool keepmin = (((lane & k) == 0) == ((lane & j) == 0));
            u64 mn = umin64(v, p), mx = umax64(v, p);
            v = keepmin ? mn : mx;
        }
    }
    return v;
}

// m, c ascending-sorted across lanes -> lowest 64 of the 128, sorted.
__device__ __forceinline__ u64 lane_merge64(u64 m, u64 c, int lane) {
    u64 cr = shfl_xor_u64(c, 63);
    u64 z = umin64(m, cr);
#pragma unroll
    for (int dd = 32; dd > 0; dd >>= 1) {
        u64 p = shfl_xor_u64(z, dd);
        u64 mn = umin64(z, p), mx = umax64(z, p);
        z = (lane & dd) ? mx : mn;
    }
    return z;
}

// One knn scan step: tau-filter + ballot-compacted LDS append + batched flush
__device__ __forceinline__ void knn_step(u64& m, u64& tau, int& cnt, u64* sbuf,
                                         float x, float y, float z,
                                         float cx, float cy, float cz,
                                         int n, int lane) {
    float d = sq3(__fsub_rn(x, cx), __fsub_rn(y, cy), __fsub_rn(z, cz));
    u64 kk = packdi(d, n);
    bool cand = kk < tau;  // strict: excluded keys provably > global 32nd
    u64 mask = __ballot(cand);
    if (mask) {
        u32 below = __builtin_amdgcn_mbcnt_hi(
            (u32)(mask >> 32), __builtin_amdgcn_mbcnt_lo((u32)mask, 0));
        if (cand) sbuf[cnt + below] = kk;
        cnt += (int)__popcll(mask);
        if (cnt >= 64) {
            u64 c = sbuf[lane];
            c = lane_sort64(c, lane);
            m = lane_merge64(m, c, lane);
            tau = shfl_u64(m, 31);
            int rem = cnt - 64;
            if (lane < rem) sbuf[lane] = sbuf[64 + lane];
            cnt = rem;
        }
    }
}

// ---------------------------------------------------------------------------
// FPS (R4/R11 champion, 418 us measured 3x): one block per batch, 256
// threads, 32 points/thread as 16 float2 pairs (contract(off): per-op IEEE
// rounding == numpy). In-loop strict-> (bd,bi) tracking per half; u64
// (d_bits,~n) pack, 6-step DPP wave argmax, single barrier, double-buffered
// 4-partial exchange, scalar b32 coord broadcasts, LDS-buffered centers.
// 7 alternative structures (R5-R10, R12-R14) all regressed -- do not touch.
// ---------------------------------------------------------------------------
__global__ __launch_bounds__(FPS_T) void fps_kernel(const float* __restrict__ in,
                                                    float* __restrict__ centers) {
#pragma clang fp contract(off)
    __shared__ float sx[NPTS];           // 32 KB
    __shared__ float sy[NPTS];           // 32 KB
    __shared__ float sz[NPTS];           // 32 KB
    __shared__ u64 s_key[2][FPS_W];      // double-buffered wave partials
    __shared__ float s_out[NGRP * 3];    // 6 KB center-coord buffer

    const int b = blockIdx.x;
    const int t = threadIdx.x;
    const int w = t >> 6;
    const float* xp = in + (size_t)b * 3 * NPTS;
    const float* yp = xp + NPTS;
    const float* zp = xp + 2 * NPTS;

    v2f xr[PPAIR], yr[PPAIR], zr[PPAIR], md[PPAIR];
#pragma unroll
    for (int i = 0; i < PPAIR; ++i) {
        int n = i * (2 * FPS_T) + 2 * t;       // pair covers points n, n+1
        xr[i] = *(const v2f*)(xp + n);
        yr[i] = *(const v2f*)(yp + n);
        zr[i] = *(const v2f*)(zp + n);
        *(v2f*)(sx + n) = xr[i];
        *(v2f*)(sy + n) = yr[i];
        *(v2f*)(sz + n) = zr[i];
        md[i] = (v2f){1e10f, 1e10f};
    }
    __syncthreads();

    int cur = 0;
    for (int r = 0; r < NGRP; ++r) {
        const float cx = sx[cur], cy = sy[cur], cz = sz[cur];  // b32 broadcasts
        if (t == 0) {  // idxs[r] is the PRE-update farthest -> buffer coords
            s_out[r * 3 + 0] = cx;
            s_out[r * 3 + 1] = cy;
            s_out[r * 3 + 2] = cz;
        }

        float bd0 = -1.0f, bd1 = -1.0f;
        int   bi0 = 0,     bi1 = 0;
#pragma unroll
        for (int i = 0; i < PPAIR; ++i) {
            v2f dx = xr[i] - cx;
            v2f dy = yr[i] - cy;
            v2f dz = zr[i] - cz;
            v2f dd = dx * dx + dy * dy + dz * dz;  // contract(off): 3 mul + 2 add
            md[i] = __builtin_elementwise_min(md[i], dd);
            int n = i * (2 * FPS_T) + 2 * t;
            if (md[i].x > bd0) { bd0 = md[i].x; bi0 = n; }      // strict >: first max
            if (md[i].y > bd1) { bd1 = md[i].y; bi1 = n + 1; }
        }
        // max (d, tie -> lowest n) == u64 max of (d_bits, ~n)
        u64 k0 = ((u64)__float_as_uint(bd0) << 32) | (u32)(~(u32)bi0);
        u64 k1 = ((u64)__float_as_uint(bd1) << 32) | (u32)(~(u32)bi1);
        u64 k = dpp_wave_max(umax64(k0, k1));
        if ((t & 63) == 63) s_key[r & 1][w] = k;  // lane 63 holds wave winner
        __syncthreads();
        u64 m = umax64(umax64(s_key[r & 1][0], s_key[r & 1][1]),
                       umax64(s_key[r & 1][2], s_key[r & 1][3]));
        cur = (int)(~(u32)m);  // recover winning index
    }

    __syncthreads();  // t0's last s_out writes
    float* cdst = centers + (size_t)b * NGRP * 3;
    for (int i = t; i < NGRP * 3; i += FPS_T) cdst[i] = s_out[i];
}

// ---------------------------------------------------------------------------
// kNN + gather: R8/R11 wave-cooperative exact top-32 core, with 4-column
// hoisted loads (12 independent loads in flight vs 3 -> 4x MLP; the scan is
// ~5x latency-bound at 165 us vs ~55 us pure-issue). Flush/merge identical.
// ---------------------------------------------------------------------------
__global__ __launch_bounds__(KNN_WPB * 64) void knn_kernel(const float* __restrict__ in,
                                                           const float* __restrict__ centers,
                                                           float* __restrict__ out) {
    __shared__ u64 sbuf[KNN_WPB][QCAP];  // 4 KB candidate buffers

    const int wave = threadIdx.x >> 6;
    const int lane = threadIdx.x & 63;
    const int cid  = blockIdx.x * KNN_WPB + wave;   // [0, B*G)
    const int b    = cid >> 9;                      // /NGRP

    const float* xp = in + (size_t)b * 3 * NPTS;
    const float* yp = xp + NPTS;
    const float* zp = xp + 2 * NPTS;

    const float cx = centers[cid * 3 + 0];
    const float cy = centers[cid * 3 + 1];
    const float cz = centers[cid * 3 + 2];

    // seed: column 0 (points 0..63), exact sorted top-64
    float x = xp[lane], y = yp[lane], z = zp[lane];
    u64 m = packdi(sq3(__fsub_rn(x, cx), __fsub_rn(y, cy), __fsub_rn(z, cz)), lane);
    m = lane_sort64(m, lane);
    u64 tau = shfl_u64(m, 31);
    int cnt = 0;  // wave-uniform buffered-candidate count

    // 4-column unrolled scan: 12 hoisted independent loads per iteration
    int j = 1;
#pragma unroll 1
    for (; j + 3 < NPTS / 64; j += 4) {
        int n0 = j * 64 + lane, n1 = n0 + 64, n2 = n0 + 128, n3 = n0 + 192;
        float x0 = xp[n0], y0 = yp[n0], z0 = zp[n0];
        float x1 = xp[n1], y1 = yp[n1], z1 = zp[n1];
        float x2 = xp[n2], y2 = yp[n2], z2 = zp[n2];
        float x3 = xp[n3], y3 = yp[n3], z3 = zp[n3];
        knn_step(m, tau, cnt, sbuf[wave], x0, y0, z0, cx, cy, cz, n0, lane);
        knn_step(m, tau, cnt, sbuf[wave], x1, y1, z1, cx, cy, cz, n1, lane);
        knn_step(m, tau, cnt, sbuf[wave], x2, y2, z2, cx, cy, cz, n2, lane);
        knn_step(m, tau, cnt, sbuf[wave], x3, y3, z3, cx, cy, cz, n3, lane);
    }
    for (; j < NPTS / 64; ++j) {
        int n = j * 64 + lane;
        knn_step(m, tau, cnt, sbuf[wave], xp[n], yp[n], zp[n], cx, cy, cz, n, lane);
    }
    // drain leftovers (<= 127 keys -> at most 2 batches)
    while (cnt > 0) {
        int take = cnt < 64 ? cnt : 64;
        u64 v = sbuf[wave][lane];
        u64 c = (lane < take) ? v : ~0ull;
        c = lane_sort64(c, lane);
        m = lane_merge64(m, c, lane);
        int rem = cnt - take;
        if (lane < rem) sbuf[wave][lane] = sbuf[wave][64 + lane];
        cnt = rem;
    }

    // lanes 0..31 hold the exact global top-32, ascending (== stable top_k)
    if (lane < KNN_K) {
        int n = (int)(u32)m;
        size_t o = (size_t)cid * (KNN_K * 3) + (size_t)lane * 3;
        out[o + 0] = __fsub_rn(xp[n], cx);
        out[o + 1] = __fsub_rn(yp[n], cy);
        out[o + 2] = __fsub_rn(zp[n], cz);
    }
}

extern "C" void kernel_launch(void* const* d_in, const int* in_sizes, int n_in,
                              void* d_out, int out_size, void* d_ws, size_t ws_size,
                              hipStream_t stream) {
    const float* in  = (const float*)d_in[0];
    float* out       = (float*)d_out;
    float* centers   = out + (size_t)BATCH * NGRP * KNN_K * 3;  // second output section

    fps_kernel<<<BATCH, FPS_T, 0, stream>>>(in, centers);
    knn_kernel<<<(BATCH * NGRP) / KNN_WPB, KNN_WPB * 64, 0, stream>>>(in, centers, out);
}